// Round 15
// baseline (39.398 us; speedup 1.0000x reference)
//
#include <hip/hip_runtime.h>
#include <hip/hip_bf16.h>

typedef float    f32x4  __attribute__((ext_vector_type(4)));
typedef float    f32x16 __attribute__((ext_vector_type(16)));
typedef short    s16x4  __attribute__((ext_vector_type(4)));
typedef short    s16x8  __attribute__((ext_vector_type(8)));
typedef unsigned u32x2  __attribute__((ext_vector_type(2)));
typedef unsigned u32x4  __attribute__((ext_vector_type(4)));
typedef __bf16   bf16x8 __attribute__((ext_vector_type(8)));

#define DEVI __device__ __forceinline__

DEVI short f2bf(float f) {
    unsigned u = __builtin_bit_cast(unsigned, f);
    u += 0x8000u;
    return (short)(u >> 16);
}
DEVI float bf2f(short s) {
    return __builtin_bit_cast(float, ((unsigned)(unsigned short)s) << 16);
}
DEVI unsigned cvt_pk_bf16(float lo, float hi) {
#if defined(__HIP_DEVICE_COMPILE__)
    unsigned r;
    asm("v_cvt_pk_bf16_f32 %0, %1, %2" : "=v"(r) : "v"(lo), "v"(hi));
    return r;
#else
    return (unsigned)(unsigned short)f2bf(lo) | ((unsigned)(unsigned short)f2bf(hi) << 16);
#endif
}

DEVI float fast_exp2(float x) {
#if defined(__HIP_DEVICE_COMPILE__) && __has_builtin(__builtin_amdgcn_exp2f)
    return __builtin_amdgcn_exp2f(x);
#else
    return exp2f(x);
#endif
}

DEVI f32x4 mfma32(s16x8 a, s16x8 b, f32x4 c) {
#if defined(__HIP_DEVICE_COMPILE__) && __has_builtin(__builtin_amdgcn_mfma_f32_16x16x32_bf16)
    return __builtin_amdgcn_mfma_f32_16x16x32_bf16(
        __builtin_bit_cast(bf16x8, a), __builtin_bit_cast(bf16x8, b), c, 0, 0, 0);
#else
    asm volatile("v_mfma_f32_16x16x32_bf16 %0, %1, %2, %0" : "+v"(c) : "v"(a), "v"(b));
    return c;
#endif
}

DEVI f32x16 mfma3216(s16x8 a, s16x8 b, f32x16 c) {
#if defined(__HIP_DEVICE_COMPILE__) && __has_builtin(__builtin_amdgcn_mfma_f32_32x32x16_bf16)
    return __builtin_amdgcn_mfma_f32_32x32x16_bf16(
        __builtin_bit_cast(bf16x8, a), __builtin_bit_cast(bf16x8, b), c, 0, 0, 0);
#else
    asm volatile("v_mfma_f32_32x32x16_bf16 %0, %1, %2, %0" : "+v"(c) : "v"(a), "v"(b));
    return c;
#endif
}

DEVI void setprio1() {
#if defined(__HIP_DEVICE_COMPILE__)
    __builtin_amdgcn_s_setprio(1);
#endif
}
DEVI void setprio0() {
#if defined(__HIP_DEVICE_COMPILE__)
    __builtin_amdgcn_s_setprio(0);
#endif
}

// async 16B global->LDS DMA. lds base is wave-uniform; HW adds lane*16.
// g must already include lane*8 shorts.
DEVI void gld_lds16(const short* g, short* ldsb, int lane) {
#if defined(__HIP_DEVICE_COMPILE__) && __has_builtin(__builtin_amdgcn_global_load_lds)
    __builtin_amdgcn_global_load_lds(
        (const __attribute__((address_space(1))) void*)g,
        (__attribute__((address_space(3))) void*)ldsb, 16, 0, 0);
#else
    *reinterpret_cast<s16x8*>(ldsb + lane * 8) =
        *reinterpret_cast<const s16x8*>(g);
#endif
}

// -------------------------------------------------------------------------
// Kernel 1: QKV projection via MFMA (unchanged from r14, passed).
//   Qg: [4][4096][64] bf16 (pre-scaled by log2(e)/8)
//   Kp: [4*64 tiles][4096] bf16 — attn LDS K-image baked into global.
//   Vp: [4*64 tiles][4096] bf16 — attn LDS V-image (permuted groups).
// -------------------------------------------------------------------------
__global__ __launch_bounds__(512) void qkv_proj(
    const float* __restrict__ x,
    const float* __restrict__ wq, const float* __restrict__ bq,
    const float* __restrict__ wk, const float* __restrict__ bk,
    const float* __restrict__ wv, const float* __restrict__ bv,
    short* __restrict__ Qg, short* __restrict__ Kp, short* __restrict__ Vp)
{
    __shared__ short Xt[32 * 64];   // [l][c], slot-swizzled

    const int b  = blockIdx.x >> 7;
    const int l0 = (blockIdx.x & 127) * 32;
    const int t  = threadIdx.x;
    const float QS = 0.18033688011112042f;   // log2(e)/sqrt(64)

    {
        const int c  = t & 63;
        const int lh = (t >> 6) * 4;
        const float* xr = x + ((size_t)b * 64 + c) * 4096 + l0 + lh;
        const float4 x0 = *reinterpret_cast<const float4*>(xr);
        float xv[4] = {x0.x, x0.y, x0.z, x0.w};
        #pragma unroll
        for (int i = 0; i < 4; ++i) {
            const int l = lh + i;
            Xt[l * 64 + (((c >> 3) ^ (l & 7)) * 8) + (c & 7)] = f2bf(xv[i]);
        }
    }

    const int lane = t & 63, w = t >> 6;
    const int g = lane >> 4, col = lane & 15;
    const int o0 = (w & 3) * 16;
    const int h  = w >> 2;

    s16x8 wqf[2], wkf[2], wvf[2];
    #pragma unroll
    for (int kc = 0; kc < 2; ++kc) {
        const int cb = 8 * g + 32 * kc;
        const float4 q0 = *reinterpret_cast<const float4*>(wq + (o0 + col) * 64 + cb);
        const float4 q1 = *reinterpret_cast<const float4*>(wq + (o0 + col) * 64 + cb + 4);
        const float4 k0 = *reinterpret_cast<const float4*>(wk + (o0 + col) * 64 + cb);
        const float4 k1 = *reinterpret_cast<const float4*>(wk + (o0 + col) * 64 + cb + 4);
        const float4 v0 = *reinterpret_cast<const float4*>(wv + (o0 + col) * 64 + cb);
        const float4 v1 = *reinterpret_cast<const float4*>(wv + (o0 + col) * 64 + cb + 4);
        wqf[kc][0] = f2bf(q0.x * QS); wqf[kc][1] = f2bf(q0.y * QS);
        wqf[kc][2] = f2bf(q0.z * QS); wqf[kc][3] = f2bf(q0.w * QS);
        wqf[kc][4] = f2bf(q1.x * QS); wqf[kc][5] = f2bf(q1.y * QS);
        wqf[kc][6] = f2bf(q1.z * QS); wqf[kc][7] = f2bf(q1.w * QS);
        wkf[kc][0] = f2bf(k0.x); wkf[kc][1] = f2bf(k0.y);
        wkf[kc][2] = f2bf(k0.z); wkf[kc][3] = f2bf(k0.w);
        wkf[kc][4] = f2bf(k1.x); wkf[kc][5] = f2bf(k1.y);
        wkf[kc][6] = f2bf(k1.z); wkf[kc][7] = f2bf(k1.w);
        wvf[kc][0] = f2bf(v0.x); wvf[kc][1] = f2bf(v0.y);
        wvf[kc][2] = f2bf(v0.z); wvf[kc][3] = f2bf(v0.w);
        wvf[kc][4] = f2bf(v1.x); wvf[kc][5] = f2bf(v1.y);
        wvf[kc][6] = f2bf(v1.z); wvf[kc][7] = f2bf(v1.w);
    }
    const f32x4 bq4 = *reinterpret_cast<const f32x4*>(bq + o0 + 4 * g);
    const f32x4 bk4 = *reinterpret_cast<const f32x4*>(bk + o0 + 4 * g);
    const float bvs = bv[o0 + col];

    __syncthreads();

    {
        const int row = h * 16 + col;
        const s16x8 xf0 = *reinterpret_cast<const s16x8*>(
            &Xt[row * 64 + ((g ^ (row & 7)) * 8)]);
        const s16x8 xf1 = *reinterpret_cast<const s16x8*>(
            &Xt[row * 64 + (((g + 4) ^ (row & 7)) * 8)]);

        f32x4 qa = bq4 * QS;
        qa = mfma32(wqf[0], xf0, qa);
        qa = mfma32(wqf[1], xf1, qa);
        f32x4 ka = bk4;
        ka = mfma32(wkf[0], xf0, ka);
        ka = mfma32(wkf[1], xf1, ka);
        f32x4 va = {bvs, bvs, bvs, bvs};
        va = mfma32(xf0, wvf[0], va);
        va = mfma32(xf1, wvf[1], va);

        s16x4 qs, ks;
        #pragma unroll
        for (int r = 0; r < 4; ++r) { qs[r] = f2bf(qa[r]); ks[r] = f2bf(ka[r]); }

        // Q: [b][l][64]
        const int l  = l0 + row;
        const int d0 = o0 + 4 * g;
        *reinterpret_cast<s16x4*>(Qg + ((size_t)b * 4096 + l) * 64 + d0) = qs;

        // K: tile-image layout
        {
            const int T  = l >> 6;
            const int rj = l & 63;
            const int off = rj * 64 + (((d0 >> 3) ^ (rj & 7)) << 3)
                          + ((d0 >> 2) & 1) * 4;
            *reinterpret_cast<s16x4*>(
                Kp + ((size_t)(b * 64 + T)) * 4096 + off) = ks;
        }

        // V: tile-image layout (permuted groups + granule XOR)
        {
            s16x4 vs;
            #pragma unroll
            for (int r = 0; r < 4; ++r) vs[r] = f2bf(va[r]);
            const int dV  = o0 + col;
            const int jgl = l0 + h * 16 + 4 * g;
            const int TV  = jgl >> 6;
            const int g4  = (jgl & 63) >> 2;
            const int p   = (g4 & 12) | ((g4 >> 1) & 1) | ((g4 & 1) << 1);
            const int off = dV * 64 + (((p >> 1) ^ (dV & 7)) << 3) + (p & 1) * 4;
            *reinterpret_cast<s16x4*>(
                Vp + ((size_t)(b * 64 + TV)) * 4096 + off) = vs;
        }
    }
}

// -------------------------------------------------------------------------
// Kernel 2: fused flash attention + residual; DMA staging (r14) with the
// wave->work re-map: 8 waves = 4 streams x 2 J-HALVES, each wave computes
// ALL 64 q of the block for its 32-j half-tile. Each K/V b128 read feeds
// TWO MFMAs (both q-subtiles) -> LDS read pipe halved per interval.
// DMA, layouts, tiles (64 j x 16 intervals), barriers: identical to r14.
// Epilogue: 8 (stream x half) partials merged via bf16 LDS overlay
// (512 rows x stride-68), normalize, residual, out.
// -------------------------------------------------------------------------
__global__ __launch_bounds__(512, 2) void attn_fused(
    const short* __restrict__ Qg, const short* __restrict__ Kp,
    const short* __restrict__ Vp, const float* __restrict__ x,
    float* __restrict__ out)
{
    __shared__ short SM[65536];   // 128KB: K [0,32768), V [32768,65536)

    const int bid = blockIdx.x;
    const int wid = (bid & 7) * 32 + (bid >> 3);   // XCD-bijective (256 = 8x32)
    const int b   = wid >> 6;
    const int qt  = wid & 63;

    const int t    = threadIdx.x;
    const int w    = t >> 6;
    const int lane = t & 63;
    const int qi   = lane & 31;
    const int hi   = lane >> 5;
    const int rx   = qi & 7;
    const int kw   = w & 3;        // compute stream
    const int h2   = w >> 2;       // j-half of each 64j tile

    // Q B-frags for BOTH q-subtiles: qf[qs][m] = Q[qt*64+qs*32+qi][16m+8hi..+8)
    s16x8 qf[2][4];
    #pragma unroll
    for (int qs = 0; qs < 2; ++qs) {
        const short* qp = Qg + ((size_t)b * 4096 + qt * 64 + qs * 32 + qi) * 64 + 8 * hi;
        qf[qs][0] = *reinterpret_cast<const s16x8*>(qp);
        qf[qs][1] = *reinterpret_cast<const s16x8*>(qp + 16);
        qf[qs][2] = *reinterpret_cast<const s16x8*>(qp + 32);
        qf[qs][3] = *reinterpret_cast<const s16x8*>(qp + 48);
    }

    // ---- DMA role (unchanged): wave w<4 -> K stream w; else V stream w-4 ----
    const int ds = w & 3;
    const short* srcb = (w < 4)
        ? (Kp + ((size_t)(b * 64 + ds * 16)) * 4096 + lane * 8)
        : (Vp + ((size_t)(b * 64 + ds * 16)) * 4096 + lane * 8);
    short* ldsb = (w < 4) ? (SM + (ds * 2) * 4096)
                          : (SM + 32768 + (ds * 2) * 4096);

    // prologue: DMA tile 0 -> buf 0
    {
        const short* s0 = srcb;
        short* l0p = ldsb;
        #pragma unroll
        for (int i = 0; i < 8; ++i)
            gld_lds16(s0 + i * 512, l0p + i * 512, lane);
    }
    __syncthreads();

    f32x16 oa00 = {}, oa01 = {}, oa10 = {}, oa11 = {};   // [qsub][dblk]
    float ls0 = 0.0f, ls1 = 0.0f;

    #pragma unroll 2
    for (int tt = 0; tt < 16; ++tt) {
        const int cur = tt & 1;
        const short* Kl = SM + (kw * 2 + cur) * 4096;
        const short* Vl = SM + 32768 + (kw * 2 + cur) * 4096;

        if (tt < 15) {   // DMA next tile into the dead buffer
            const short* s1 = srcb + (size_t)(tt + 1) * 4096;
            short* l1p = ldsb + (cur ^ 1) * 4096;
            #pragma unroll
            for (int i = 0; i < 8; ++i)
                gld_lds16(s1 + i * 512, l1p + i * 512, lane);
        }

        // ---- K frags for this wave's j-half (read ONCE, used twice) ----
        const short* kr = Kl + (h2 * 32 + qi) * 64;
        s16x8 ka[4];
        #pragma unroll
        for (int m = 0; m < 4; ++m)
            ka[m] = *reinterpret_cast<const s16x8*>(kr + (((2 * m + hi) ^ rx) * 8));

        // ---- QK^T for both q-subtiles ----
        f32x16 S0 = {}, S1 = {};
        setprio1();
        #pragma unroll
        for (int m = 0; m < 4; ++m) S0 = mfma3216(ka[m], qf[0][m], S0);
        #pragma unroll
        for (int m = 0; m < 4; ++m) S1 = mfma3216(ka[m], qf[1][m], S1);
        setprio0();

        // ---- V frags for this j-half (read ONCE, used twice) ----
        const short* vr0 = Vl + qi * 64;
        const short* vr1 = Vl + (32 + qi) * 64;
        const int sA0 = ((4 * h2 + 0 + hi) ^ rx) * 8;
        const int sA1 = ((4 * h2 + 2 + hi) ^ rx) * 8;
        const s16x8 va00 = *reinterpret_cast<const s16x8*>(vr0 + sA0);
        const s16x8 va10 = *reinterpret_cast<const s16x8*>(vr1 + sA0);
        const s16x8 va01 = *reinterpret_cast<const s16x8*>(vr0 + sA1);
        const s16x8 va11 = *reinterpret_cast<const s16x8*>(vr1 + sA1);

        // ---- P = exp2(S) (fixed max: exact here), pack, sums ----
        unsigned P0[8], P1[8];
        float ps0 = 0.0f, ps1 = 0.0f;
        #pragma unroll
        for (int i = 0; i < 8; ++i) {
            const float e0 = fast_exp2(S0[2 * i]);
            const float e1 = fast_exp2(S0[2 * i + 1]);
            ps0 += e0 + e1;
            P0[i] = cvt_pk_bf16(e0, e1);
            const float f0 = fast_exp2(S1[2 * i]);
            const float f1 = fast_exp2(S1[2 * i + 1]);
            ps1 += f0 + f1;
            P1[i] = cvt_pk_bf16(f0, f1);
        }
        ls0 += ps0; ls1 += ps1;
        const u32x4 w00 = {P0[0], P0[1], P0[2], P0[3]};
        const u32x4 w01 = {P0[4], P0[5], P0[6], P0[7]};
        const u32x4 w10 = {P1[0], P1[1], P1[2], P1[3]};
        const u32x4 w11 = {P1[4], P1[5], P1[6], P1[7]};

        // ---- PV: each V frag feeds both q-subtiles ----
        setprio1();
        oa00 = mfma3216(va00, __builtin_bit_cast(s16x8, w00), oa00);
        oa01 = mfma3216(va10, __builtin_bit_cast(s16x8, w00), oa01);
        oa10 = mfma3216(va00, __builtin_bit_cast(s16x8, w10), oa10);
        oa11 = mfma3216(va10, __builtin_bit_cast(s16x8, w10), oa11);
        oa00 = mfma3216(va01, __builtin_bit_cast(s16x8, w01), oa00);
        oa01 = mfma3216(va11, __builtin_bit_cast(s16x8, w01), oa01);
        oa10 = mfma3216(va01, __builtin_bit_cast(s16x8, w11), oa10);
        oa11 = mfma3216(va11, __builtin_bit_cast(s16x8, w11), oa11);
        setprio0();

        __syncthreads();   // reads of buf cur done; DMA into cur^1 drained
    }

    // per-qsub l totals over this (stream, half): both hi halves
    const float lt0 = ls0 + __shfl_xor(ls0, 32);
    const float lt1 = ls1 + __shfl_xor(ls1, 32);

    // ---- epilogue: merge 8 (stream x half) partials, bf16 LDS overlay ----
    // Po[512 rows][68 shorts]; row = w*64 + qsub*32 + qi. Lf f32[512] after.
    short* Po = SM;
    float* Lf = reinterpret_cast<float*>(SM + 512 * 68);
    {
        const int row0 = w * 64 + qi;
        const int row1 = w * 64 + 32 + qi;
        #pragma unroll
        for (int db = 0; db < 2; ++db) {
            const f32x16 a0 = db ? oa01 : oa00;
            const f32x16 a1 = db ? oa11 : oa10;
            #pragma unroll
            for (int rq = 0; rq < 4; ++rq) {
                const int dbase = 8 * rq + 4 * hi + 32 * db;
                u32x2 pk0, pk1;
                pk0[0] = cvt_pk_bf16(a0[4 * rq + 0], a0[4 * rq + 1]);
                pk0[1] = cvt_pk_bf16(a0[4 * rq + 2], a0[4 * rq + 3]);
                pk1[0] = cvt_pk_bf16(a1[4 * rq + 0], a1[4 * rq + 1]);
                pk1[1] = cvt_pk_bf16(a1[4 * rq + 2], a1[4 * rq + 3]);
                *reinterpret_cast<u32x2*>(&Po[row0 * 68 + dbase]) = pk0;
                *reinterpret_cast<u32x2*>(&Po[row1 * 68 + dbase]) = pk1;
            }
        }
        if (hi == 0) {
            Lf[row0] = lt0;
            Lf[row1] = lt1;
        }
    }
    __syncthreads();

    // ---- final: sum 8 partials, normalize, residual, coalesced out ----
    {
        const int q  = t & 63;          // lane -> consecutive q (coalesced)
        const int dst = (t >> 6) * 8;   // wave handles 8 d's
        float acc[8] = {};
        float L = 0.0f;
        #pragma unroll
        for (int s = 0; s < 8; ++s) {
            const int row = s * 64 + q;
            L += Lf[row];
            const s16x4 o0 = *reinterpret_cast<const s16x4*>(&Po[row * 68 + dst]);
            const s16x4 o1 = *reinterpret_cast<const s16x4*>(&Po[row * 68 + dst + 4]);
            #pragma unroll
            for (int i = 0; i < 4; ++i) {
                acc[i]     += bf2f(o0[i]);
                acc[4 + i] += bf2f(o1[i]);
            }
        }
        const float rL = 1.0f / L;
        const size_t ob = ((size_t)b * 64 + dst) * 4096 + qt * 64 + q;
        #pragma unroll
        for (int i = 0; i < 8; ++i) {
            const size_t idx = ob + (size_t)i * 4096;
            out[idx] = fmaf(acc[i], rL, x[idx]);
        }
    }
}

extern "C" void kernel_launch(void* const* d_in, const int* in_sizes, int n_in,
                              void* d_out, int out_size, void* d_ws, size_t ws_size,
                              hipStream_t stream) {
    const float* x  = (const float*)d_in[0];
    const float* wq = (const float*)d_in[1];
    const float* bq = (const float*)d_in[2];
    const float* wk = (const float*)d_in[3];
    const float* bk = (const float*)d_in[4];
    const float* wv = (const float*)d_in[5];
    const float* bv = (const float*)d_in[6];
    float* out = (float*)d_out;

    short* Qg = reinterpret_cast<short*>(d_ws);    // [4][4096][64]     2MB
    short* Kp = Qg + (size_t)4 * 4096 * 64;        // [256 tiles][4096] 2MB
    short* Vp = Kp + (size_t)4 * 4096 * 64;        // [256 tiles][4096] 2MB

    qkv_proj<<<dim3(512), dim3(512), 0, stream>>>(x, wq, bq, wk, bk, wv, bv, Qg, Kp, Vp);
    attn_fused<<<dim3(256), dim3(512), 0, stream>>>(Qg, Kp, Vp, x, out);
}